// Round 6
// baseline (180.777 us; speedup 1.0000x reference)
//
#include <hip/hip_runtime.h>
#include <hip/hip_bf16.h>

#define HIDDEN 256
#define HEADS 8
#define HEAD_DIM 32
#define NUM_RBF 32
#define K_PTS 4096
#define N_ATOMS 2048
#define B_MOL 32
#define ATOMS_PER_MOL (N_ATOMS / B_MOL)   // 64

typedef __attribute__((ext_vector_type(8))) short bf16x8;
typedef __attribute__((ext_vector_type(4))) float f32x4;

// -------------------------------------------------------------------------
// K0: prepW — weight transposes (4 mats x 64 tiles of 32x32). WT[c][d]=bf16(W[d][c])
// -------------------------------------------------------------------------
__global__ __launch_bounds__(256) void prepW_kernel(
    const float* __restrict__ Wq, const float* __restrict__ Wk,
    const float* __restrict__ Wv, const float* __restrict__ Wo,
    __hip_bfloat16* __restrict__ WqT, __hip_bfloat16* __restrict__ WkT,
    __hip_bfloat16* __restrict__ WvT, __hip_bfloat16* __restrict__ WoT) {
    __shared__ float tile[32][33];
    const int t = blockIdx.x, tid = threadIdx.x;
    const int matId = t >> 6, tileId = t & 63;
    const int tr = (tileId >> 3) * 32, tc = (tileId & 7) * 32;
    const float* __restrict__ Ws = (matId == 0) ? Wq : (matId == 1) ? Wk : (matId == 2) ? Wv : Wo;
    __hip_bfloat16* __restrict__ Wd = (matId == 0) ? WqT : (matId == 1) ? WkT : (matId == 2) ? WvT : WoT;

    const int r = tid >> 3, cq = (tid & 7) * 4;
    const float4 in = *(const float4*)&Ws[(size_t)(tr + r) * HIDDEN + tc + cq];
    tile[r][cq + 0] = in.x; tile[r][cq + 1] = in.y;
    tile[r][cq + 2] = in.z; tile[r][cq + 3] = in.w;
    __syncthreads();
    __hip_bfloat16 o[4];
    o[0] = __float2bfloat16(tile[cq + 0][r]);
    o[1] = __float2bfloat16(tile[cq + 1][r]);
    o[2] = __float2bfloat16(tile[cq + 2][r]);
    o[3] = __float2bfloat16(tile[cq + 3][r]);
    *(uint2*)(Wd + (size_t)(tc + r) * HIDDEN + tr + cq) = *(const uint2*)o;
}

// -------------------------------------------------------------------------
// K1: fused QKV MFMA GEMM, f32 inputs converted to bf16 fragments on load.
// Q -> f32 q_ws; K,V -> bf16 (halves attn read traffic).
// -------------------------------------------------------------------------
__device__ __forceinline__ bf16x8 cvt8(const float* p) {
    const float4 lo = *(const float4*)p;
    const float4 hi = *(const float4*)(p + 4);
    __hip_bfloat16 t[8];
    t[0] = __float2bfloat16(lo.x); t[1] = __float2bfloat16(lo.y);
    t[2] = __float2bfloat16(lo.z); t[3] = __float2bfloat16(lo.w);
    t[4] = __float2bfloat16(hi.x); t[5] = __float2bfloat16(hi.y);
    t[6] = __float2bfloat16(hi.z); t[7] = __float2bfloat16(hi.w);
    return *(const bf16x8*)t;
}

__global__ __launch_bounds__(256) void qkv2_kernel(
    const float* __restrict__ hp, const float* __restrict__ ha,
    const __hip_bfloat16* __restrict__ WqT, const float* __restrict__ bq, float* __restrict__ q_ws,
    const __hip_bfloat16* __restrict__ WkT, const float* __restrict__ bk, __hip_bfloat16* __restrict__ k_bf,
    const __hip_bfloat16* __restrict__ WvT, const float* __restrict__ bv, __hip_bfloat16* __restrict__ v_bf) {
    const bool isQ = (blockIdx.x < 256);
    const float* __restrict__ A = isQ ? hp : ha;
    const __hip_bfloat16* __restrict__ W0T = isQ ? WqT : WkT;
    const float* __restrict__ b0 = isQ ? bq : bk;
    const int r0 = (isQ ? blockIdx.x : blockIdx.x - 256) * 16;

    const int wave = threadIdx.x >> 6, lane = threadIdx.x & 63;
    const int c0 = wave * 64;
    const int lrow = lane & 15, kgrp = lane >> 4;

    bf16x8 af[8];
    const float* Arow = A + (size_t)(r0 + lrow) * HIDDEN + kgrp * 8;
#pragma unroll
    for (int ks = 0; ks < 8; ++ks)
        af[ks] = cvt8(Arow + ks * 32);

    f32x4 acc0[4], acc1[4];
#pragma unroll
    for (int cc = 0; cc < 4; ++cc) {
        acc0[cc] = (f32x4){0.f, 0.f, 0.f, 0.f};
        acc1[cc] = (f32x4){0.f, 0.f, 0.f, 0.f};
    }

#pragma unroll
    for (int cc = 0; cc < 4; ++cc) {
        const short* W0r = (const short*)W0T + (size_t)(c0 + cc * 16 + lrow) * HIDDEN + kgrp * 8;
#pragma unroll
        for (int ks = 0; ks < 8; ++ks)
            acc0[cc] = __builtin_amdgcn_mfma_f32_16x16x32_bf16(
                af[ks], *(const bf16x8*)(W0r + ks * 32), acc0[cc], 0, 0, 0);
        if (!isQ) {
            const short* W1r = (const short*)WvT + (size_t)(c0 + cc * 16 + lrow) * HIDDEN + kgrp * 8;
#pragma unroll
            for (int ks = 0; ks < 8; ++ks)
                acc1[cc] = __builtin_amdgcn_mfma_f32_16x16x32_bf16(
                    af[ks], *(const bf16x8*)(W1r + ks * 32), acc1[cc], 0, 0, 0);
        }
    }

    const int colb = lane & 15;
    const int rowb = (lane >> 4) * 4;
#pragma unroll
    for (int cc = 0; cc < 4; ++cc) {
        const int cgl = c0 + cc * 16 + colb;
        const float bias0 = b0[cgl];
        if (isQ) {
#pragma unroll
            for (int rg = 0; rg < 4; ++rg)
                q_ws[(size_t)(r0 + rowb + rg) * HIDDEN + cgl] = acc0[cc][rg] + bias0;
        } else {
            const float bias1 = bv[cgl];
#pragma unroll
            for (int rg = 0; rg < 4; ++rg) {
                k_bf[(size_t)(r0 + rowb + rg) * HIDDEN + cgl] = __float2bfloat16(acc0[cc][rg] + bias0);
                v_bf[(size_t)(r0 + rowb + rg) * HIDDEN + cgl] = __float2bfloat16(acc1[cc][rg] + bias1);
            }
        }
    }
}

// -------------------------------------------------------------------------
// K2: attn_oln4 — block = 4 points, wave = (4 points x 2 heads), lane = atom.
// bf16 K/V; per-wave K read = 2-head slice only; PV by output column.
// Fused out-projection MFMA (4-row tile) + residual + layernorm.
// -------------------------------------------------------------------------
#define W_PAD 72
#define AGG_PAD (HIDDEN + 16)

__device__ __forceinline__ void unpack2(unsigned u, float& lo, float& hi) {
    lo = __uint_as_float(u << 16);
    hi = __uint_as_float(u & 0xffff0000u);
}

__global__ __launch_bounds__(256) void attn_oln4_kernel(
    const float* __restrict__ q, const __hip_bfloat16* __restrict__ kmat,
    const __hip_bfloat16* __restrict__ vmat,
    const float* __restrict__ pos_point, const float* __restrict__ pos_atom,
    const float* __restrict__ W_rbf, const float* __restrict__ b_rbf,
    const float* __restrict__ centers,
    const int* __restrict__ point_batch, const int* __restrict__ atom_batch,
    const __hip_bfloat16* __restrict__ WoT, const float* __restrict__ bo,
    const float* __restrict__ h_point,
    const float* __restrict__ gamma, const float* __restrict__ beta,
    float* __restrict__ out) {
    __shared__ float q_lds[4][260];                // 4.2 KB (260-stride: float4-aligned)
    __shared__ float wrbf_lds[NUM_RBF][HEADS];     // 1 KB
    __shared__ float cent_lds[NUM_RBF];
    __shared__ float brbf_lds[HEADS];
    __shared__ float p_lds[4][2][4][W_PAD];        // 9.2 KB [wave][hl][pt][atom]
    __shared__ __hip_bfloat16 agg_lds[4][AGG_PAD]; // 2.2 KB
    __shared__ float x_lds[4][260];                // 4.2 KB
    __shared__ float red_s[4][4];
    __shared__ float red_q[4][4];

    const int tid = threadIdx.x, wave = tid >> 6, lane = tid & 63;
    const int j0 = blockIdx.x * 4;

    {   // stage 4 q rows (1 float4/thread)
        const int row = tid >> 6, c4 = (tid & 63) * 4;
        *(float4*)&q_lds[row][c4] = *(const float4*)(q + (size_t)(j0 + row) * HIDDEN + c4);
    }
    ((float*)wrbf_lds)[tid & 255] = W_rbf[tid & 255];
    if (tid < NUM_RBF) cent_lds[tid] = centers[tid];
    if (tid < HEADS) brbf_lds[tid] = b_rbf[tid];
    __syncthreads();

    const int m = point_batch[j0];
    const int n = m * ATOMS_PER_MOL + lane;
    const bool valid = (atom_batch[n] == m);
    const int h0 = wave * 2;   // this wave's heads: h0, h0+1

    // distances for 4 points vs this lane's atom
    const float ax = pos_atom[n * 3 + 0], ay = pos_atom[n * 3 + 1], az = pos_atom[n * 3 + 2];
    float dist[4];
#pragma unroll
    for (int p = 0; p < 4; ++p) {
        const float dx = pos_point[(j0 + p) * 3 + 0] - ax;
        const float dy = pos_point[(j0 + p) * 3 + 1] - ay;
        const float dz = pos_point[(j0 + p) * 3 + 2] - az;
        dist[p] = sqrtf(fmaxf(dx * dx + dy * dy + dz * dz, 0.0f));
    }

    // RBF bias for this wave's 2 heads, 4 points. -1/width = -16
    float bias[4][2];
#pragma unroll
    for (int p = 0; p < 4; ++p) {
        bias[p][0] = brbf_lds[h0];
        bias[p][1] = brbf_lds[h0 + 1];
    }
#pragma unroll
    for (int r = 0; r < NUM_RBF; ++r) {
        const float cr = cent_lds[r];
        const float w0 = wrbf_lds[r][h0], w1 = wrbf_lds[r][h0 + 1];
#pragma unroll
        for (int p = 0; p < 4; ++p) {
            const float dd = dist[p] - cr;
            const float e = __expf(-16.0f * dd * dd);
            bias[p][0] += e * w0;
            bias[p][1] += e * w1;
        }
    }

    const float scale = 0.17677669529663687f;  // 32^-0.5

    // QK^T + softmax per (head-local hl, point)
#pragma unroll
    for (int hl = 0; hl < 2; ++hl) {
        const unsigned* kr = (const unsigned*)((const unsigned short*)kmat +
                             (size_t)n * HIDDEN + (h0 + hl) * HEAD_DIM);
        float kf[32];
#pragma unroll
        for (int i = 0; i < 16; ++i)
            unpack2(kr[i], kf[2 * i], kf[2 * i + 1]);

        float dot[4] = {0.f, 0.f, 0.f, 0.f};
#pragma unroll
        for (int i = 0; i < 8; ++i) {
            const int qo = (h0 + hl) * HEAD_DIM + i * 4;
            const float4 q0 = *(const float4*)&q_lds[0][qo];
            const float4 q1 = *(const float4*)&q_lds[1][qo];
            const float4 q2 = *(const float4*)&q_lds[2][qo];
            const float4 q3 = *(const float4*)&q_lds[3][qo];
            dot[0] += q0.x * kf[4*i] + q0.y * kf[4*i+1] + q0.z * kf[4*i+2] + q0.w * kf[4*i+3];
            dot[1] += q1.x * kf[4*i] + q1.y * kf[4*i+1] + q1.z * kf[4*i+2] + q1.w * kf[4*i+3];
            dot[2] += q2.x * kf[4*i] + q2.y * kf[4*i+1] + q2.z * kf[4*i+2] + q2.w * kf[4*i+3];
            dot[3] += q3.x * kf[4*i] + q3.y * kf[4*i+1] + q3.z * kf[4*i+2] + q3.w * kf[4*i+3];
        }
#pragma unroll
        for (int p = 0; p < 4; ++p) {
            float score = valid ? (dot[p] * scale + bias[p][hl]) : -1e30f;
            float mx = score;
#pragma unroll
            for (int off = 32; off > 0; off >>= 1)
                mx = fmaxf(mx, __shfl_xor(mx, off));
            const float e = __expf(score - mx);
            float ss = e;
#pragma unroll
            for (int off = 32; off > 0; off >>= 1)
                ss += __shfl_xor(ss, off);
            p_lds[wave][hl][p][lane] = e / ss;   // wave-local: no barrier needed
        }
    }

    // PV: thread owns output column c = tid (head = c>>5 matches this wave's heads)
    {
        const int c = tid;
        const int hl2 = (lane >> 5) & 1;
        const unsigned short* vbase = (const unsigned short*)vmat +
                                      (size_t)(m * ATOMS_PER_MOL) * HIDDEN + c;
        float acc[4] = {0.f, 0.f, 0.f, 0.f};
#pragma unroll
        for (int ag = 0; ag < ATOMS_PER_MOL / 4; ++ag) {
            const float4 p0 = *(const float4*)&p_lds[wave][hl2][0][ag * 4];
            const float4 p1 = *(const float4*)&p_lds[wave][hl2][1][ag * 4];
            const float4 p2 = *(const float4*)&p_lds[wave][hl2][2][ag * 4];
            const float4 p3 = *(const float4*)&p_lds[wave][hl2][3][ag * 4];
            const float* pp0 = (const float*)&p0;
            const float* pp1 = (const float*)&p1;
            const float* pp2 = (const float*)&p2;
            const float* pp3 = (const float*)&p3;
#pragma unroll
            for (int i = 0; i < 4; ++i) {
                const int a = ag * 4 + i;
                const float v = __uint_as_float(((unsigned)vbase[(size_t)a * HIDDEN]) << 16);
                acc[0] += pp0[i] * v;
                acc[1] += pp1[i] * v;
                acc[2] += pp2[i] * v;
                acc[3] += pp3[i] * v;
            }
        }
#pragma unroll
        for (int p = 0; p < 4; ++p)
            agg_lds[p][c] = __float2bfloat16(acc[p]);
    }
    __syncthreads();

    // ---- out-projection MFMA: 4 valid rows (4-15 zero), 256 cols ----
    const int c0 = wave * 64;
    const int lrow = lane & 15, kgrp = lane >> 4;
    bf16x8 af[8];
    const bf16x8 zf = {0, 0, 0, 0, 0, 0, 0, 0};
#pragma unroll
    for (int ks = 0; ks < 8; ++ks)
        af[ks] = (lrow < 4) ? *(const bf16x8*)(&agg_lds[lrow & 3][kgrp * 8 + ks * 32]) : zf;

    f32x4 acc[4];
#pragma unroll
    for (int cc = 0; cc < 4; ++cc) acc[cc] = (f32x4){0.f, 0.f, 0.f, 0.f};
#pragma unroll
    for (int cc = 0; cc < 4; ++cc) {
        const short* Wr = (const short*)WoT + (size_t)(c0 + cc * 16 + lrow) * HIDDEN + kgrp * 8;
#pragma unroll
        for (int ks = 0; ks < 8; ++ks)
            acc[cc] = __builtin_amdgcn_mfma_f32_16x16x32_bf16(
                af[ks], *(const bf16x8*)(Wr + ks * 32), acc[cc], 0, 0, 0);
    }

    // x = proj + bias + residual for rows 0..3
    const int colb = lane & 15;
    const int rowb = (lane >> 4) * 4;
#pragma unroll
    for (int cc = 0; cc < 4; ++cc) {
        const int cgl = c0 + cc * 16 + colb;
        const float bias_o = bo[cgl];
#pragma unroll
        for (int rg = 0; rg < 4; ++rg) {
            const int rl = rowb + rg;
            if (rl < 4)
                x_lds[rl][cgl] = acc[cc][rg] + bias_o + h_point[(size_t)(j0 + rl) * HIDDEN + cgl];
        }
    }
    __syncthreads();

    // ---- layernorm over 4 rows ----
    const int c = tid;
    const int ln = c & 63, wv = c >> 6;
    float xv[4];
#pragma unroll
    for (int r = 0; r < 4; ++r) {
        xv[r] = x_lds[r][c];
        float s = xv[r], qq = xv[r] * xv[r];
#pragma unroll
        for (int off = 32; off > 0; off >>= 1) {
            s += __shfl_xor(s, off);
            qq += __shfl_xor(qq, off);
        }
        if (ln == 0) { red_s[r][wv] = s; red_q[r][wv] = qq; }
    }
    __syncthreads();

    const float gc = gamma[c], bc = beta[c];
#pragma unroll
    for (int r = 0; r < 4; ++r) {
        const float mean = (red_s[r][0] + red_s[r][1] + red_s[r][2] + red_s[r][3]) * (1.0f / HIDDEN);
        const float ex2  = (red_q[r][0] + red_q[r][1] + red_q[r][2] + red_q[r][3]) * (1.0f / HIDDEN);
        const float var = ex2 - mean * mean;
        out[(size_t)(j0 + r) * HIDDEN + c] = (xv[r] - mean) * rsqrtf(var + 1e-5f) * gc + bc;
    }
}

// -------------------------------------------------------------------------
extern "C" void kernel_launch(void* const* d_in, const int* in_sizes, int n_in,
                              void* d_out, int out_size, void* d_ws, size_t ws_size,
                              hipStream_t stream) {
    const float* h_point   = (const float*)d_in[0];
    const float* h_atom    = (const float*)d_in[1];
    const float* pos_point = (const float*)d_in[2];
    const float* pos_atom  = (const float*)d_in[3];
    const float* Wq        = (const float*)d_in[4];
    const float* bq        = (const float*)d_in[5];
    const float* Wk        = (const float*)d_in[6];
    const float* bk        = (const float*)d_in[7];
    const float* Wv        = (const float*)d_in[8];
    const float* bv        = (const float*)d_in[9];
    const float* Wo        = (const float*)d_in[10];
    const float* bo        = (const float*)d_in[11];
    const float* W_rbf     = (const float*)d_in[12];
    const float* b_rbf     = (const float*)d_in[13];
    const float* centers   = (const float*)d_in[14];
    const float* gamma     = (const float*)d_in[15];
    const float* beta      = (const float*)d_in[16];
    const int*   point_batch = (const int*)d_in[17];
    const int*   atom_batch  = (const int*)d_in[18];
    float* out = (float*)d_out;

    float* q_ws = (float*)d_ws;                                      // 4096*256 f32
    __hip_bfloat16* k_bf = (__hip_bfloat16*)(q_ws + (size_t)K_PTS * HIDDEN);
    __hip_bfloat16* v_bf = k_bf + (size_t)N_ATOMS * HIDDEN;
    __hip_bfloat16* WqT = v_bf + (size_t)N_ATOMS * HIDDEN;
    __hip_bfloat16* WkT = WqT + HIDDEN * HIDDEN;
    __hip_bfloat16* WvT = WkT + HIDDEN * HIDDEN;
    __hip_bfloat16* WoT = WvT + HIDDEN * HIDDEN;

    prepW_kernel<<<256, 256, 0, stream>>>(Wq, Wk, Wv, Wo, WqT, WkT, WvT, WoT);

    qkv2_kernel<<<384, 256, 0, stream>>>(h_point, h_atom,
                                         WqT, bq, q_ws,
                                         WkT, bk, k_bf,
                                         WvT, bv, v_bf);

    attn_oln4_kernel<<<K_PTS / 4, 256, 0, stream>>>(q_ws, k_bf, v_bf,
                                                    pos_point, pos_atom,
                                                    W_rbf, b_rbf, centers,
                                                    point_batch, atom_batch,
                                                    WoT, bo, h_point, gamma, beta,
                                                    out);
}

// Round 8
// 137.078 us; speedup vs baseline: 1.3188x; 1.3188x over previous
//
#include <hip/hip_runtime.h>
#include <hip/hip_bf16.h>

#define HIDDEN 256
#define HEADS 8
#define HEAD_DIM 32
#define NUM_RBF 32
#define K_PTS 4096
#define N_ATOMS 2048
#define B_MOL 32
#define ATOMS_PER_MOL (N_ATOMS / B_MOL)   // 64

typedef __attribute__((ext_vector_type(8))) short bf16x8;
typedef __attribute__((ext_vector_type(4))) float f32x4;

// -------------------------------------------------------------------------
// K0: prepW — weight transposes (4 mats x 64 tiles of 32x32). WT[c][d]=bf16(W[d][c])
// -------------------------------------------------------------------------
__global__ __launch_bounds__(256) void prepW_kernel(
    const float* __restrict__ Wq, const float* __restrict__ Wk,
    const float* __restrict__ Wv, const float* __restrict__ Wo,
    __hip_bfloat16* __restrict__ WqT, __hip_bfloat16* __restrict__ WkT,
    __hip_bfloat16* __restrict__ WvT, __hip_bfloat16* __restrict__ WoT) {
    __shared__ float tile[32][33];
    const int t = blockIdx.x, tid = threadIdx.x;
    const int matId = t >> 6, tileId = t & 63;
    const int tr = (tileId >> 3) * 32, tc = (tileId & 7) * 32;
    const float* __restrict__ Ws = (matId == 0) ? Wq : (matId == 1) ? Wk : (matId == 2) ? Wv : Wo;
    __hip_bfloat16* __restrict__ Wd = (matId == 0) ? WqT : (matId == 1) ? WkT : (matId == 2) ? WvT : WoT;

    const int r = tid >> 3, cq = (tid & 7) * 4;
    const float4 in = *(const float4*)&Ws[(size_t)(tr + r) * HIDDEN + tc + cq];
    tile[r][cq + 0] = in.x; tile[r][cq + 1] = in.y;
    tile[r][cq + 2] = in.z; tile[r][cq + 3] = in.w;
    __syncthreads();
    __hip_bfloat16 o[4];
    o[0] = __float2bfloat16(tile[cq + 0][r]);
    o[1] = __float2bfloat16(tile[cq + 1][r]);
    o[2] = __float2bfloat16(tile[cq + 2][r]);
    o[3] = __float2bfloat16(tile[cq + 3][r]);
    *(uint2*)(Wd + (size_t)(tc + r) * HIDDEN + tr + cq) = *(const uint2*)o;
}

// -------------------------------------------------------------------------
// K1: fused QKV MFMA GEMM. Q -> bf16 row-major; K -> bf16 row-major;
// V -> bf16 TRANSPOSED [col 256][atom 2048] (for PV MFMA B fragments).
// -------------------------------------------------------------------------
__device__ __forceinline__ bf16x8 cvt8(const float* p) {
    const float4 lo = *(const float4*)p;
    const float4 hi = *(const float4*)(p + 4);
    __hip_bfloat16 t[8];
    t[0] = __float2bfloat16(lo.x); t[1] = __float2bfloat16(lo.y);
    t[2] = __float2bfloat16(lo.z); t[3] = __float2bfloat16(lo.w);
    t[4] = __float2bfloat16(hi.x); t[5] = __float2bfloat16(hi.y);
    t[6] = __float2bfloat16(hi.z); t[7] = __float2bfloat16(hi.w);
    return *(const bf16x8*)t;
}

__global__ __launch_bounds__(256) void qkv3_kernel(
    const float* __restrict__ hp, const float* __restrict__ ha,
    const __hip_bfloat16* __restrict__ WqT, const float* __restrict__ bq, __hip_bfloat16* __restrict__ qb,
    const __hip_bfloat16* __restrict__ WkT, const float* __restrict__ bk, __hip_bfloat16* __restrict__ kb,
    const __hip_bfloat16* __restrict__ WvT, const float* __restrict__ bv, __hip_bfloat16* __restrict__ vt) {
    const bool isQ = (blockIdx.x < 256);
    const float* __restrict__ A = isQ ? hp : ha;
    const __hip_bfloat16* __restrict__ W0T = isQ ? WqT : WkT;
    const float* __restrict__ b0 = isQ ? bq : bk;
    const int r0 = (isQ ? blockIdx.x : blockIdx.x - 256) * 16;

    const int wave = threadIdx.x >> 6, lane = threadIdx.x & 63;
    const int c0 = wave * 64;
    const int lrow = lane & 15, kgrp = lane >> 4;

    bf16x8 af[8];
    const float* Arow = A + (size_t)(r0 + lrow) * HIDDEN + kgrp * 8;
#pragma unroll
    for (int ks = 0; ks < 8; ++ks)
        af[ks] = cvt8(Arow + ks * 32);

    f32x4 acc0[4], acc1[4];
#pragma unroll
    for (int cc = 0; cc < 4; ++cc) {
        acc0[cc] = (f32x4){0.f, 0.f, 0.f, 0.f};
        acc1[cc] = (f32x4){0.f, 0.f, 0.f, 0.f};
    }

#pragma unroll
    for (int cc = 0; cc < 4; ++cc) {
        const short* W0r = (const short*)W0T + (size_t)(c0 + cc * 16 + lrow) * HIDDEN + kgrp * 8;
#pragma unroll
        for (int ks = 0; ks < 8; ++ks)
            acc0[cc] = __builtin_amdgcn_mfma_f32_16x16x32_bf16(
                af[ks], *(const bf16x8*)(W0r + ks * 32), acc0[cc], 0, 0, 0);
        if (!isQ) {
            const short* W1r = (const short*)WvT + (size_t)(c0 + cc * 16 + lrow) * HIDDEN + kgrp * 8;
#pragma unroll
            for (int ks = 0; ks < 8; ++ks)
                acc1[cc] = __builtin_amdgcn_mfma_f32_16x16x32_bf16(
                    af[ks], *(const bf16x8*)(W1r + ks * 32), acc1[cc], 0, 0, 0);
        }
    }

    const int colb = lane & 15;
    const int rowb = (lane >> 4) * 4;
#pragma unroll
    for (int cc = 0; cc < 4; ++cc) {
        const int cgl = c0 + cc * 16 + colb;
        const float bias0 = b0[cgl];
        if (isQ) {
#pragma unroll
            for (int rg = 0; rg < 4; ++rg)
                qb[(size_t)(r0 + rowb + rg) * HIDDEN + cgl] = __float2bfloat16(acc0[cc][rg] + bias0);
        } else {
            const float bias1 = bv[cgl];
#pragma unroll
            for (int rg = 0; rg < 4; ++rg) {
                kb[(size_t)(r0 + rowb + rg) * HIDDEN + cgl] = __float2bfloat16(acc0[cc][rg] + bias0);
                vt[(size_t)cgl * N_ATOMS + (r0 + rowb + rg)] = __float2bfloat16(acc1[cc][rg] + bias1);
            }
        }
    }
}

// -------------------------------------------------------------------------
// K2: attn_mfma — block = 8 points (one molecule slice), 4 waves.
// Phase 1 (lane=atom, wave=2pts): RBF bias scalar -> bias_lds[h][atom][pt]
// Phase 2 (wave=2 heads): QK^T via MFMA (A=Q bf16 global, B=K bf16 global),
//   bias via ds_read_b128, softmax in-register, P -> p_lds bf16.
// Phase 3: PV via MFMA (A=P from LDS, B=V^T bf16 global) -> agg_lds bf16.
// Phase 4: out-proj MFMA + residual + layernorm (as R5).
// -------------------------------------------------------------------------
#define AGG_PAD (HIDDEN + 16)

__global__ __launch_bounds__(256) void attn_mfma_kernel(
    const __hip_bfloat16* __restrict__ qb, const __hip_bfloat16* __restrict__ kb,
    const __hip_bfloat16* __restrict__ vt,
    const float* __restrict__ pos_point, const float* __restrict__ pos_atom,
    const float* __restrict__ W_rbf, const float* __restrict__ b_rbf,
    const float* __restrict__ centers,
    const int* __restrict__ point_batch, const int* __restrict__ atom_batch,
    const __hip_bfloat16* __restrict__ WoT, const float* __restrict__ bo,
    const float* __restrict__ h_point,
    const float* __restrict__ gamma, const float* __restrict__ beta,
    float* __restrict__ out) {
    __shared__ float wrbf_lds[NUM_RBF][HEADS];      // 1 KB
    __shared__ float cent_lds[NUM_RBF];
    __shared__ float brbf_lds[HEADS];
    __shared__ float bias_lds[HEADS][ATOMS_PER_MOL + 1][8];  // 16.6 KB, +1 row pad for b128 overreach
    __shared__ __hip_bfloat16 p_lds[HEADS][8][72];  // 9 KB [h][pt][atom], 144B row stride (16B-aligned)
    __shared__ __hip_bfloat16 agg_lds[8][AGG_PAD];  // 4.3 KB
    __shared__ float x_lds[8][260];                 // 8.3 KB
    __shared__ float red_s[8][4];
    __shared__ float red_q[8][4];

    const int tid = threadIdx.x, wave = tid >> 6, lane = tid & 63;
    const int j0 = blockIdx.x * 8;
    const float scale = 0.17677669529663687f;  // 32^-0.5

    ((float*)wrbf_lds)[tid] = W_rbf[tid];
    if (tid < NUM_RBF) cent_lds[tid] = centers[tid];
    if (tid < HEADS) brbf_lds[tid] = b_rbf[tid];
    if (tid < 64) {   // zero the pad row (read by discarded kgrp>=2 lanes)
        bias_lds[tid >> 3][ATOMS_PER_MOL][tid & 7] = 0.0f;
    }
    __syncthreads();

    const int m = point_batch[j0];
    const int mbase = m * ATOMS_PER_MOL;

    // ---------------- Phase 1: RBF bias (lane = atom, wave = 2 points) ----
    {
        const int n = mbase + lane;
        const bool valid = (atom_batch[n] == m);
        const int jA = j0 + wave * 2, jB = jA + 1;

        const float ax = pos_atom[n * 3 + 0], ay = pos_atom[n * 3 + 1], az = pos_atom[n * 3 + 2];
        const float dxA = pos_point[jA * 3 + 0] - ax;
        const float dyA = pos_point[jA * 3 + 1] - ay;
        const float dzA = pos_point[jA * 3 + 2] - az;
        const float dxB = pos_point[jB * 3 + 0] - ax;
        const float dyB = pos_point[jB * 3 + 1] - ay;
        const float dzB = pos_point[jB * 3 + 2] - az;
        const float distA = sqrtf(fmaxf(dxA * dxA + dyA * dyA + dzA * dzA, 0.0f));
        const float distB = sqrtf(fmaxf(dxB * dxB + dyB * dyB + dzB * dzB, 0.0f));

        float biasA[HEADS], biasB[HEADS];
#pragma unroll
        for (int h = 0; h < HEADS; ++h) { biasA[h] = brbf_lds[h]; biasB[h] = brbf_lds[h]; }
#pragma unroll
        for (int r = 0; r < NUM_RBF; ++r) {
            const float cr = cent_lds[r];
            const float ddA = distA - cr, ddB = distB - cr;
            const float eA = __expf(-16.0f * ddA * ddA);   // width = (8/32)^2 -> -1/w = -16
            const float eB = __expf(-16.0f * ddB * ddB);
#pragma unroll
            for (int h = 0; h < HEADS; ++h) {
                const float wr = wrbf_lds[r][h];
                biasA[h] += eA * wr;
                biasB[h] += eB * wr;
            }
        }
#pragma unroll
        for (int h = 0; h < HEADS; ++h) {
            bias_lds[h][lane][wave * 2 + 0] = valid ? biasA[h] : -1e30f;
            bias_lds[h][lane][wave * 2 + 1] = valid ? biasB[h] : -1e30f;
        }
    }
    __syncthreads();

    // ---------------- Phase 2+3: per-head QK^T MFMA, softmax, PV MFMA -----
    const int c = lane & 15, kgrp = lane >> 4;
    const int h0 = wave * 2;

#pragma unroll
    for (int hl = 0; hl < 2; ++hl) {
        const int h = h0 + hl;

        // A fragment: Q rows = points (rows 8-15 duplicate 0-7, outputs unused)
        const bf16x8 aq = *(const bf16x8*)((const short*)qb +
                          (size_t)(j0 + (c & 7)) * HIDDEN + h * HEAD_DIM + kgrp * 8);

        // QK^T: one MFMA per 16-atom tile (K=32 = head_dim)
        f32x4 sacc[4];
#pragma unroll
        for (int t = 0; t < 4; ++t) {
            const bf16x8 bk_ = *(const bf16x8*)((const short*)kb +
                               (size_t)(mbase + c + 16 * t) * HIDDEN + h * HEAD_DIM + kgrp * 8);
            sacc[t] = __builtin_amdgcn_mfma_f32_16x16x32_bf16(
                aq, bk_, (f32x4){0.f, 0.f, 0.f, 0.f}, 0, 0, 0);
        }

        // scores + bias (one b128 per tile = 4 point-rows), then softmax
        float s[4][4];   // [tile][reg=pt row]
#pragma unroll
        for (int t = 0; t < 4; ++t) {
            const f32x4 bv = *(const f32x4*)&bias_lds[h][c + 16 * t][kgrp * 4];
#pragma unroll
            for (int r = 0; r < 4; ++r)
                s[t][r] = sacc[t][r] * scale + bv[r];
        }
#pragma unroll
        for (int r = 0; r < 4; ++r) {
            float mx = fmaxf(fmaxf(s[0][r], s[1][r]), fmaxf(s[2][r], s[3][r]));
#pragma unroll
            for (int off = 1; off <= 8; off <<= 1)
                mx = fmaxf(mx, __shfl_xor(mx, off));
            float e0 = __expf(s[0][r] - mx);
            float e1 = __expf(s[1][r] - mx);
            float e2 = __expf(s[2][r] - mx);
            float e3 = __expf(s[3][r] - mx);
            float ss = e0 + e1 + e2 + e3;
#pragma unroll
            for (int off = 1; off <= 8; off <<= 1)
                ss += __shfl_xor(ss, off);
            const float inv = 1.0f / ss;
            if (kgrp < 2) {   // rows 0-7 = valid points
                const int pt = kgrp * 4 + r;
                p_lds[h][pt][c + 16 * 0] = __float2bfloat16(e0 * inv);
                p_lds[h][pt][c + 16 * 1] = __float2bfloat16(e1 * inv);
                p_lds[h][pt][c + 16 * 2] = __float2bfloat16(e2 * inv);
                p_lds[h][pt][c + 16 * 3] = __float2bfloat16(e3 * inv);
            }
        }

        // PV: A = P (LDS, row=pt), B = V^T (global, col-rows), 2 n-tiles x 2 ksteps
#pragma unroll
        for (int t2 = 0; t2 < 2; ++t2) {
            f32x4 pacc = (f32x4){0.f, 0.f, 0.f, 0.f};
#pragma unroll
            for (int ks = 0; ks < 2; ++ks) {
                const bf16x8 ap = *(const bf16x8*)&p_lds[h][c & 7][ks * 32 + kgrp * 8];
                const bf16x8 bvv = *(const bf16x8*)((const short*)vt +
                                   (size_t)(h * HEAD_DIM + t2 * 16 + c) * N_ATOMS +
                                   mbase + ks * 32 + kgrp * 8);
                pacc = __builtin_amdgcn_mfma_f32_16x16x32_bf16(ap, bvv, pacc, 0, 0, 0);
            }
            if (kgrp < 2) {
#pragma unroll
                for (int r = 0; r < 4; ++r)
                    agg_lds[kgrp * 4 + r][h * HEAD_DIM + t2 * 16 + c] = __float2bfloat16(pacc[r]);
            }
        }
    }
    __syncthreads();

    // ---------------- Phase 4: out-projection MFMA + residual + LN --------
    const int c0 = wave * 64;
    const int lrow = lane & 15, kgrp2 = lane >> 4;
    bf16x8 af[8];
    const bf16x8 zf = {0, 0, 0, 0, 0, 0, 0, 0};
#pragma unroll
    for (int ks = 0; ks < 8; ++ks)
        af[ks] = (lrow < 8) ? *(const bf16x8*)(&agg_lds[lrow & 7][kgrp2 * 8 + ks * 32]) : zf;

    f32x4 oacc[4];
#pragma unroll
    for (int cc = 0; cc < 4; ++cc) oacc[cc] = (f32x4){0.f, 0.f, 0.f, 0.f};
#pragma unroll
    for (int cc = 0; cc < 4; ++cc) {
        const short* Wr = (const short*)WoT + (size_t)(c0 + cc * 16 + lrow) * HIDDEN + kgrp2 * 8;
#pragma unroll
        for (int ks = 0; ks < 8; ++ks)
            oacc[cc] = __builtin_amdgcn_mfma_f32_16x16x32_bf16(
                af[ks], *(const bf16x8*)(Wr + ks * 32), oacc[cc], 0, 0, 0);
    }

    const int colb = lane & 15;
    const int rowb = (lane >> 4) * 4;
#pragma unroll
    for (int cc = 0; cc < 4; ++cc) {
        const int cgl = c0 + cc * 16 + colb;
        const float bias_o = bo[cgl];
#pragma unroll
        for (int rg = 0; rg < 4; ++rg) {
            const int rl = rowb + rg;
            if (rl < 8)
                x_lds[rl][cgl] = oacc[cc][rg] + bias_o + h_point[(size_t)(j0 + rl) * HIDDEN + cgl];
        }
    }
    __syncthreads();

    const int cc2 = tid;
    const int ln = cc2 & 63, wv = cc2 >> 6;
    float xv[8];
#pragma unroll
    for (int r = 0; r < 8; ++r) {
        xv[r] = x_lds[r][cc2];
        float s = xv[r], qq = xv[r] * xv[r];
#pragma unroll
        for (int off = 32; off > 0; off >>= 1) {
            s += __shfl_xor(s, off);
            qq += __shfl_xor(qq, off);
        }
        if (ln == 0) { red_s[r][wv] = s; red_q[r][wv] = qq; }
    }
    __syncthreads();

    const float gc = gamma[cc2], bc = beta[cc2];
#pragma unroll
    for (int r = 0; r < 8; ++r) {
        const float mean = (red_s[r][0] + red_s[r][1] + red_s[r][2] + red_s[r][3]) * (1.0f / HIDDEN);
        const float ex2  = (red_q[r][0] + red_q[r][1] + red_q[r][2] + red_q[r][3]) * (1.0f / HIDDEN);
        const float var = ex2 - mean * mean;
        out[(size_t)(j0 + r) * HIDDEN + cc2] = (xv[r] - mean) * rsqrtf(var + 1e-5f) * gc + bc;
    }
}

// -------------------------------------------------------------------------
extern "C" void kernel_launch(void* const* d_in, const int* in_sizes, int n_in,
                              void* d_out, int out_size, void* d_ws, size_t ws_size,
                              hipStream_t stream) {
    const float* h_point   = (const float*)d_in[0];
    const float* h_atom    = (const float*)d_in[1];
    const float* pos_point = (const float*)d_in[2];
    const float* pos_atom  = (const float*)d_in[3];
    const float* Wq        = (const float*)d_in[4];
    const float* bq        = (const float*)d_in[5];
    const float* Wk        = (const float*)d_in[6];
    const float* bk        = (const float*)d_in[7];
    const float* Wv        = (const float*)d_in[8];
    const float* bv        = (const float*)d_in[9];
    const float* Wo        = (const float*)d_in[10];
    const float* bo        = (const float*)d_in[11];
    const float* W_rbf     = (const float*)d_in[12];
    const float* b_rbf     = (const float*)d_in[13];
    const float* centers   = (const float*)d_in[14];
    const float* gamma     = (const float*)d_in[15];
    const float* beta      = (const float*)d_in[16];
    const int*   point_batch = (const int*)d_in[17];
    const int*   atom_batch  = (const int*)d_in[18];
    float* out = (float*)d_out;

    __hip_bfloat16* qb = (__hip_bfloat16*)d_ws;                 // 4096*256 bf16
    __hip_bfloat16* kb = qb + (size_t)K_PTS * HIDDEN;           // 2048*256 bf16
    __hip_bfloat16* vt = kb + (size_t)N_ATOMS * HIDDEN;         // 256*2048 bf16 (transposed)
    __hip_bfloat16* WqT = vt + (size_t)HIDDEN * N_ATOMS;
    __hip_bfloat16* WkT = WqT + HIDDEN * HIDDEN;
    __hip_bfloat16* WvT = WkT + HIDDEN * HIDDEN;
    __hip_bfloat16* WoT = WvT + HIDDEN * HIDDEN;

    prepW_kernel<<<256, 256, 0, stream>>>(Wq, Wk, Wv, Wo, WqT, WkT, WvT, WoT);

    qkv3_kernel<<<384, 256, 0, stream>>>(h_point, h_atom,
                                         WqT, bq, qb,
                                         WkT, bk, kb,
                                         WvT, bv, vt);

    attn_mfma_kernel<<<K_PTS / 8, 256, 0, stream>>>(qb, kb, vt,
                                                    pos_point, pos_atom,
                                                    W_rbf, b_rbf, centers,
                                                    point_batch, atom_batch,
                                                    WoT, bo, h_point, gamma, beta,
                                                    out);
}

// Round 10
// 133.010 us; speedup vs baseline: 1.3591x; 1.0306x over previous
//
#include <hip/hip_runtime.h>
#include <hip/hip_bf16.h>

#define HIDDEN 256
#define HEADS 8
#define HEAD_DIM 32
#define NUM_RBF 32
#define K_PTS 4096
#define N_ATOMS 2048
#define B_MOL 32
#define ATOMS_PER_MOL (N_ATOMS / B_MOL)   // 64

typedef __attribute__((ext_vector_type(8))) short bf16x8;
typedef __attribute__((ext_vector_type(4))) float f32x4;

// -------------------------------------------------------------------------
// K0: prepW — weight transposes (4 mats x 64 tiles of 32x32). WT[c][d]=bf16(W[d][c])
// -------------------------------------------------------------------------
__global__ __launch_bounds__(256) void prepW_kernel(
    const float* __restrict__ Wq, const float* __restrict__ Wk,
    const float* __restrict__ Wv, const float* __restrict__ Wo,
    __hip_bfloat16* __restrict__ WqT, __hip_bfloat16* __restrict__ WkT,
    __hip_bfloat16* __restrict__ WvT, __hip_bfloat16* __restrict__ WoT) {
    __shared__ float tile[32][33];
    const int t = blockIdx.x, tid = threadIdx.x;
    const int matId = t >> 6, tileId = t & 63;
    const int tr = (tileId >> 3) * 32, tc = (tileId & 7) * 32;
    const float* __restrict__ Ws = (matId == 0) ? Wq : (matId == 1) ? Wk : (matId == 2) ? Wv : Wo;
    __hip_bfloat16* __restrict__ Wd = (matId == 0) ? WqT : (matId == 1) ? WkT : (matId == 2) ? WvT : WoT;

    const int r = tid >> 3, cq = (tid & 7) * 4;
    const float4 in = *(const float4*)&Ws[(size_t)(tr + r) * HIDDEN + tc + cq];
    tile[r][cq + 0] = in.x; tile[r][cq + 1] = in.y;
    tile[r][cq + 2] = in.z; tile[r][cq + 3] = in.w;
    __syncthreads();
    __hip_bfloat16 o[4];
    o[0] = __float2bfloat16(tile[cq + 0][r]);
    o[1] = __float2bfloat16(tile[cq + 1][r]);
    o[2] = __float2bfloat16(tile[cq + 2][r]);
    o[3] = __float2bfloat16(tile[cq + 3][r]);
    *(uint2*)(Wd + (size_t)(tc + r) * HIDDEN + tr + cq) = *(const uint2*)o;
}

// -------------------------------------------------------------------------
// K1: fused QKV MFMA GEMM. Q -> bf16 row-major; K -> bf16 row-major;
// V -> bf16 TRANSPOSED [col 256][atom 2048] (for PV MFMA B fragments).
// -------------------------------------------------------------------------
__device__ __forceinline__ bf16x8 cvt8(const float* p) {
    const float4 lo = *(const float4*)p;
    const float4 hi = *(const float4*)(p + 4);
    __hip_bfloat16 t[8];
    t[0] = __float2bfloat16(lo.x); t[1] = __float2bfloat16(lo.y);
    t[2] = __float2bfloat16(lo.z); t[3] = __float2bfloat16(lo.w);
    t[4] = __float2bfloat16(hi.x); t[5] = __float2bfloat16(hi.y);
    t[6] = __float2bfloat16(hi.z); t[7] = __float2bfloat16(hi.w);
    return *(const bf16x8*)t;
}

__global__ __launch_bounds__(256) void qkv3_kernel(
    const float* __restrict__ hp, const float* __restrict__ ha,
    const __hip_bfloat16* __restrict__ WqT, const float* __restrict__ bq, __hip_bfloat16* __restrict__ qb,
    const __hip_bfloat16* __restrict__ WkT, const float* __restrict__ bk, __hip_bfloat16* __restrict__ kb,
    const __hip_bfloat16* __restrict__ WvT, const float* __restrict__ bv, __hip_bfloat16* __restrict__ vt) {
    const bool isQ = (blockIdx.x < 256);
    const float* __restrict__ A = isQ ? hp : ha;
    const __hip_bfloat16* __restrict__ W0T = isQ ? WqT : WkT;
    const float* __restrict__ b0 = isQ ? bq : bk;
    const int r0 = (isQ ? blockIdx.x : blockIdx.x - 256) * 16;

    const int wave = threadIdx.x >> 6, lane = threadIdx.x & 63;
    const int c0 = wave * 64;
    const int lrow = lane & 15, kgrp = lane >> 4;

    bf16x8 af[8];
    const float* Arow = A + (size_t)(r0 + lrow) * HIDDEN + kgrp * 8;
#pragma unroll
    for (int ks = 0; ks < 8; ++ks)
        af[ks] = cvt8(Arow + ks * 32);

    f32x4 acc0[4], acc1[4];
#pragma unroll
    for (int cc = 0; cc < 4; ++cc) {
        acc0[cc] = (f32x4){0.f, 0.f, 0.f, 0.f};
        acc1[cc] = (f32x4){0.f, 0.f, 0.f, 0.f};
    }

#pragma unroll
    for (int cc = 0; cc < 4; ++cc) {
        const short* W0r = (const short*)W0T + (size_t)(c0 + cc * 16 + lrow) * HIDDEN + kgrp * 8;
#pragma unroll
        for (int ks = 0; ks < 8; ++ks)
            acc0[cc] = __builtin_amdgcn_mfma_f32_16x16x32_bf16(
                af[ks], *(const bf16x8*)(W0r + ks * 32), acc0[cc], 0, 0, 0);
        if (!isQ) {
            const short* W1r = (const short*)WvT + (size_t)(c0 + cc * 16 + lrow) * HIDDEN + kgrp * 8;
#pragma unroll
            for (int ks = 0; ks < 8; ++ks)
                acc1[cc] = __builtin_amdgcn_mfma_f32_16x16x32_bf16(
                    af[ks], *(const bf16x8*)(W1r + ks * 32), acc1[cc], 0, 0, 0);
        }
    }

    const int colb = lane & 15;
    const int rowb = (lane >> 4) * 4;
#pragma unroll
    for (int cc = 0; cc < 4; ++cc) {
        const int cgl = c0 + cc * 16 + colb;
        const float bias0 = b0[cgl];
        if (isQ) {
#pragma unroll
            for (int rg = 0; rg < 4; ++rg)
                qb[(size_t)(r0 + rowb + rg) * HIDDEN + cgl] = __float2bfloat16(acc0[cc][rg] + bias0);
        } else {
            const float bias1 = bv[cgl];
#pragma unroll
            for (int rg = 0; rg < 4; ++rg) {
                kb[(size_t)(r0 + rowb + rg) * HIDDEN + cgl] = __float2bfloat16(acc0[cc][rg] + bias0);
                vt[(size_t)cgl * N_ATOMS + (r0 + rowb + rg)] = __float2bfloat16(acc1[cc][rg] + bias1);
            }
        }
    }
}

// -------------------------------------------------------------------------
// K2: attn_mfma8 — block = 8 points, 8 WAVES (512 threads).
// Phase 1 (wave = 1 point, lane = atom): RBF bias -> bias_lds[h][atom][pt]
// Phase 2+3 (wave = 1 head): QK^T MFMA + softmax + PV MFMA
// Phase 4: out-proj MFMA (wave = 32 cols) + residual + LN (thread = 4 rows)
// -------------------------------------------------------------------------
#define AGG_PAD (HIDDEN + 16)

__global__ __launch_bounds__(512) void attn_mfma8_kernel(
    const __hip_bfloat16* __restrict__ qb, const __hip_bfloat16* __restrict__ kb,
    const __hip_bfloat16* __restrict__ vt,
    const float* __restrict__ pos_point, const float* __restrict__ pos_atom,
    const float* __restrict__ W_rbf, const float* __restrict__ b_rbf,
    const float* __restrict__ centers,
    const int* __restrict__ point_batch, const int* __restrict__ atom_batch,
    const __hip_bfloat16* __restrict__ WoT, const float* __restrict__ bo,
    const float* __restrict__ h_point,
    const float* __restrict__ gamma, const float* __restrict__ beta,
    float* __restrict__ out) {
    __shared__ float wrbf_lds[NUM_RBF][HEADS];      // 1 KB
    __shared__ float cent_lds[NUM_RBF];
    __shared__ float brbf_lds[HEADS];
    __shared__ float bias_lds[HEADS][ATOMS_PER_MOL + 1][8];  // 16.6 KB (+1 row pad)
    __shared__ __hip_bfloat16 p_lds[HEADS][8][72];  // 9 KB [h][pt][atom]
    __shared__ __hip_bfloat16 agg_lds[8][AGG_PAD];  // 4.3 KB
    __shared__ float x_lds[8][260];                 // 8.3 KB
    __shared__ float red_s[8][4];
    __shared__ float red_q[8][4];

    const int tid = threadIdx.x, wave = tid >> 6, lane = tid & 63;
    const int j0 = blockIdx.x * 8;
    const float scale = 0.17677669529663687f;  // 32^-0.5

    if (tid < NUM_RBF * HEADS) ((float*)wrbf_lds)[tid] = W_rbf[tid];
    if (tid < NUM_RBF) cent_lds[tid] = centers[tid];
    if (tid < HEADS) brbf_lds[tid] = b_rbf[tid];
    if (tid < 64) bias_lds[tid >> 3][ATOMS_PER_MOL][tid & 7] = 0.0f;  // pad row
    __syncthreads();

    const int m = point_batch[j0];
    const int mbase = m * ATOMS_PER_MOL;

    // ---------------- Phase 1: RBF bias (wave = 1 point, lane = atom) ----
    {
        const int n = mbase + lane;
        const bool valid = (atom_batch[n] == m);
        const int j = j0 + wave;

        const float dx = pos_point[j * 3 + 0] - pos_atom[n * 3 + 0];
        const float dy = pos_point[j * 3 + 1] - pos_atom[n * 3 + 1];
        const float dz = pos_point[j * 3 + 2] - pos_atom[n * 3 + 2];
        const float dist = sqrtf(fmaxf(dx * dx + dy * dy + dz * dz, 0.0f));

        float bias[HEADS];
#pragma unroll
        for (int h = 0; h < HEADS; ++h) bias[h] = brbf_lds[h];
#pragma unroll
        for (int r = 0; r < NUM_RBF; ++r) {
            const float dd = dist - cent_lds[r];
            const float e = __expf(-16.0f * dd * dd);   // width = (8/32)^2 -> -1/w = -16
#pragma unroll
            for (int h = 0; h < HEADS; ++h)
                bias[h] += e * wrbf_lds[r][h];
        }
#pragma unroll
        for (int h = 0; h < HEADS; ++h)
            bias_lds[h][lane][wave] = valid ? bias[h] : -1e30f;
    }
    __syncthreads();

    // ---------------- Phase 2+3: wave = 1 head ---------------------------
    const int c = lane & 15, kgrp = lane >> 4;
    const int h = wave;
    {
        // A fragment: Q rows = points (rows 8-15 duplicate 0-7, outputs unused)
        const bf16x8 aq = *(const bf16x8*)((const short*)qb +
                          (size_t)(j0 + (c & 7)) * HIDDEN + h * HEAD_DIM + kgrp * 8);

        // QK^T: one MFMA per 16-atom tile (K=32 = head_dim)
        f32x4 sacc[4];
#pragma unroll
        for (int t = 0; t < 4; ++t) {
            const bf16x8 bk_ = *(const bf16x8*)((const short*)kb +
                               (size_t)(mbase + c + 16 * t) * HIDDEN + h * HEAD_DIM + kgrp * 8);
            sacc[t] = __builtin_amdgcn_mfma_f32_16x16x32_bf16(
                aq, bk_, (f32x4){0.f, 0.f, 0.f, 0.f}, 0, 0, 0);
        }

        // scores + bias, then softmax over atoms (reduce across 16-lane c-group)
        float s[4][4];   // [tile][reg = pt row]
#pragma unroll
        for (int t = 0; t < 4; ++t) {
            const f32x4 bv = *(const f32x4*)&bias_lds[h][c + 16 * t][kgrp * 4];
#pragma unroll
            for (int r = 0; r < 4; ++r)
                s[t][r] = sacc[t][r] * scale + bv[r];
        }
#pragma unroll
        for (int r = 0; r < 4; ++r) {
            float mx = fmaxf(fmaxf(s[0][r], s[1][r]), fmaxf(s[2][r], s[3][r]));
#pragma unroll
            for (int off = 1; off <= 8; off <<= 1)
                mx = fmaxf(mx, __shfl_xor(mx, off));
            float e0 = __expf(s[0][r] - mx);
            float e1 = __expf(s[1][r] - mx);
            float e2 = __expf(s[2][r] - mx);
            float e3 = __expf(s[3][r] - mx);
            float ss = e0 + e1 + e2 + e3;
#pragma unroll
            for (int off = 1; off <= 8; off <<= 1)
                ss += __shfl_xor(ss, off);
            const float inv = 1.0f / ss;
            if (kgrp < 2) {   // rows 0-7 = valid points
                const int pt = kgrp * 4 + r;
                p_lds[h][pt][c + 16 * 0] = __float2bfloat16(e0 * inv);
                p_lds[h][pt][c + 16 * 1] = __float2bfloat16(e1 * inv);
                p_lds[h][pt][c + 16 * 2] = __float2bfloat16(e2 * inv);
                p_lds[h][pt][c + 16 * 3] = __float2bfloat16(e3 * inv);
            }
        }

        // PV: A = P (LDS, row=pt), B = V^T (global), 2 n-tiles x 2 k-steps
#pragma unroll
        for (int t2 = 0; t2 < 2; ++t2) {
            f32x4 pacc = (f32x4){0.f, 0.f, 0.f, 0.f};
#pragma unroll
            for (int ks = 0; ks < 2; ++ks) {
                const bf16x8 ap = *(const bf16x8*)&p_lds[h][c & 7][ks * 32 + kgrp * 8];
                const bf16x8 bvv = *(const bf16x8*)((const short*)vt +
                                   (size_t)(h * HEAD_DIM + t2 * 16 + c) * N_ATOMS +
                                   mbase + ks * 32 + kgrp * 8);
                pacc = __builtin_amdgcn_mfma_f32_16x16x32_bf16(ap, bvv, pacc, 0, 0, 0);
            }
            if (kgrp < 2) {
#pragma unroll
                for (int r = 0; r < 4; ++r)
                    agg_lds[kgrp * 4 + r][h * HEAD_DIM + t2 * 16 + c] = __float2bfloat16(pacc[r]);
            }
        }
    }
    __syncthreads();

    // ---------------- Phase 4: out-projection MFMA (wave = 32 cols) ------
    const int c0 = wave * 32;
    const int lrow = lane & 15, kgrp2 = lane >> 4;
    bf16x8 af[8];
    const bf16x8 zf = {0, 0, 0, 0, 0, 0, 0, 0};
#pragma unroll
    for (int ks = 0; ks < 8; ++ks)
        af[ks] = (lrow < 8) ? *(const bf16x8*)(&agg_lds[lrow & 7][kgrp2 * 8 + ks * 32]) : zf;

    f32x4 oacc[2];
#pragma unroll
    for (int cc = 0; cc < 2; ++cc) oacc[cc] = (f32x4){0.f, 0.f, 0.f, 0.f};
#pragma unroll
    for (int cc = 0; cc < 2; ++cc) {
        const short* Wr = (const short*)WoT + (size_t)(c0 + cc * 16 + lrow) * HIDDEN + kgrp2 * 8;
#pragma unroll
        for (int ks = 0; ks < 8; ++ks)
            oacc[cc] = __builtin_amdgcn_mfma_f32_16x16x32_bf16(
                af[ks], *(const bf16x8*)(Wr + ks * 32), oacc[cc], 0, 0, 0);
    }

    const int colb = lane & 15;
    const int rowb = (lane >> 4) * 4;
#pragma unroll
    for (int cc = 0; cc < 2; ++cc) {
        const int cgl = c0 + cc * 16 + colb;
        const float bias_o = bo[cgl];
#pragma unroll
        for (int rg = 0; rg < 4; ++rg) {
            const int rl = rowb + rg;
            if (rl < 8)
                x_lds[rl][cgl] = oacc[cc][rg] + bias_o + h_point[(size_t)(j0 + rl) * HIDDEN + cgl];
        }
    }
    __syncthreads();

    // ---------------- LN: 512 threads, col = tid&255, 4 rows each --------
    const int col = tid & 255;
    const int half = tid >> 8;             // 0: rows 0-3, 1: rows 4-7
    const int ln = col & 63, wv = col >> 6;
    float xv[4];
#pragma unroll
    for (int r = 0; r < 4; ++r) {
        const int rr = half * 4 + r;
        xv[r] = x_lds[rr][col];
        float s = xv[r], qq = xv[r] * xv[r];
#pragma unroll
        for (int off = 32; off > 0; off >>= 1) {
            s += __shfl_xor(s, off);
            qq += __shfl_xor(qq, off);
        }
        if (ln == 0) { red_s[rr][wv] = s; red_q[rr][wv] = qq; }
    }
    __syncthreads();

    const float gc = gamma[col], bc = beta[col];
#pragma unroll
    for (int r = 0; r < 4; ++r) {
        const int rr = half * 4 + r;
        const float mean = (red_s[rr][0] + red_s[rr][1] + red_s[rr][2] + red_s[rr][3]) * (1.0f / HIDDEN);
        const float ex2  = (red_q[rr][0] + red_q[rr][1] + red_q[rr][2] + red_q[rr][3]) * (1.0f / HIDDEN);
        const float var = ex2 - mean * mean;
        out[(size_t)(j0 + rr) * HIDDEN + col] = (xv[r] - mean) * rsqrtf(var + 1e-5f) * gc + bc;
    }
}

// -------------------------------------------------------------------------
extern "C" void kernel_launch(void* const* d_in, const int* in_sizes, int n_in,
                              void* d_out, int out_size, void* d_ws, size_t ws_size,
                              hipStream_t stream) {
    const float* h_point   = (const float*)d_in[0];
    const float* h_atom    = (const float*)d_in[1];
    const float* pos_point = (const float*)d_in[2];
    const float* pos_atom  = (const float*)d_in[3];
    const float* Wq        = (const float*)d_in[4];
    const float* bq        = (const float*)d_in[5];
    const float* Wk        = (const float*)d_in[6];
    const float* bk        = (const float*)d_in[7];
    const float* Wv        = (const float*)d_in[8];
    const float* bv        = (const float*)d_in[9];
    const float* Wo        = (const float*)d_in[10];
    const float* bo        = (const float*)d_in[11];
    const float* W_rbf     = (const float*)d_in[12];
    const float* b_rbf     = (const float*)d_in[13];
    const float* centers   = (const float*)d_in[14];
    const float* gamma     = (const float*)d_in[15];
    const float* beta      = (const float*)d_in[16];
    const int*   point_batch = (const int*)d_in[17];
    const int*   atom_batch  = (const int*)d_in[18];
    float* out = (float*)d_out;

    __hip_bfloat16* qb = (__hip_bfloat16*)d_ws;                 // 4096*256 bf16
    __hip_bfloat16* kb = qb + (size_t)K_PTS * HIDDEN;           // 2048*256 bf16
    __hip_bfloat16* vt = kb + (size_t)N_ATOMS * HIDDEN;         // 256*2048 bf16 (transposed)
    __hip_bfloat16* WqT = vt + (size_t)HIDDEN * N_ATOMS;
    __hip_bfloat16* WkT = WqT + HIDDEN * HIDDEN;
    __hip_bfloat16* WvT = WkT + HIDDEN * HIDDEN;
    __hip_bfloat16* WoT = WvT + HIDDEN * HIDDEN;

    prepW_kernel<<<256, 256, 0, stream>>>(Wq, Wk, Wv, Wo, WqT, WkT, WvT, WoT);

    qkv3_kernel<<<384, 256, 0, stream>>>(h_point, h_atom,
                                         WqT, bq, qb,
                                         WkT, bk, kb,
                                         WvT, bv, vt);

    attn_mfma8_kernel<<<K_PTS / 8, 512, 0, stream>>>(qb, kb, vt,
                                                     pos_point, pos_atom,
                                                     W_rbf, b_rbf, centers,
                                                     point_batch, atom_batch,
                                                     WoT, bo, h_point, gamma, beta,
                                                     out);
}